// Round 11
// baseline (825.655 us; speedup 1.0000x reference)
//
#include <hip/hip_runtime.h>
#include <hip/hip_fp16.h>
#include <cstddef>
#include <cstdint>

typedef _Float16 f16;
typedef _Float16 f16x8 __attribute__((ext_vector_type(8)));
typedef _Float16 f16x4 __attribute__((ext_vector_type(4)));
typedef float    f32x4 __attribute__((ext_vector_type(4)));

#define BK 64   // K-tile depth (fp16 elems); 2 MFMA k-steps per tile

// async 16B global->LDS (linear LDS dest = wave-uniform base + lane*16)
__device__ __forceinline__ void gload16(const void* g, void* lds) {
  __builtin_amdgcn_global_load_lds(
      (const __attribute__((address_space(1))) unsigned int*)g,
      (__attribute__((address_space(3))) unsigned int*)lds, 16, 0, 0);
}

// Stage an [R x 64] fp16 tile via global_load_lds. LDS row r holds global
// 8-elem slot s at slot s^(r&7) (rule-21 both-sides swizzle).
template<int R>
__device__ __forceinline__ void stage_f16(f16 (*buf)[BK], const f16* __restrict__ src,
                                          int ld, int w, int lane) {
#pragma unroll
  for (int i = 0; i < R / 32; i++) {
    const int grp  = w * (R / 32) + i;          // wave-uniform
    const int r    = grp * 8 + (lane >> 3);
    const int slot = (lane & 7) ^ (r & 7);
    gload16(src + (size_t)r * ld + slot * 8, &buf[grp * 8][0]);
  }
}

// Reg-staging for f32 sources (T14 issue-early / write-late).
template<int R>
struct RegStage {
  static constexpr int NV = (R == 128) ? 8 : 4;
  float4 v[NV];
  __device__ __forceinline__ void load(const float* __restrict__ src, int ld, int tid) {
    const int r = (R == 128) ? (tid >> 1) : (tid >> 2);
    const int h = (R == 128) ? (tid & 1) * 32 : (tid & 3) * 16;
    const float* p = src + (size_t)r * ld + h;
#pragma unroll
    for (int j = 0; j < NV; j++) v[j] = ((const float4*)p)[j];
  }
  __device__ __forceinline__ void write(f16 (*buf)[BK], int tid) {
    const int r = (R == 128) ? (tid >> 1) : (tid >> 2);
    const int h = (R == 128) ? (tid & 1) * 32 : (tid & 3) * 16;
#pragma unroll
    for (int g = 0; g < NV / 2; g++) {
      const float4 a = v[g * 2], b = v[g * 2 + 1];
      f16x8 o;
      o[0] = (f16)a.x; o[1] = (f16)a.y; o[2] = (f16)a.z; o[3] = (f16)a.w;
      o[4] = (f16)b.x; o[5] = (f16)b.y; o[6] = (f16)b.z; o[7] = (f16)b.w;
      const int slot = (h / 8 + g) ^ (r & 7);
      *(f16x8*)&buf[r][slot * 8] = o;
    }
  }
};

// ---------------------------------------------------------------------------
// TN GEMM, double-buffered (R5-proven core): C = A@B^T (+bias[n]) (+relu).
// fp16 operands: global_load_lds. f32 operands: reg-stage + cvt.
// Chunked bijective XCD swizzle on (bx,by); requires nxy % 8 == 0.
// ---------------------------------------------------------------------------
template<int BMt, int BNt, typename TA, typename TB, bool BIAS, bool RELU, typename TC>
__global__ __launch_bounds__(256, 2)
void gemm_tn(const TA* __restrict__ A, int lda,
             const TB* __restrict__ B, int ldb,
             TC* __restrict__ C, int ldc,
             const float* __restrict__ bias, int K)
{
  constexpr int MF = BMt / 32;
  constexpr int NF = BNt / 32;
  __shared__ f16 As[2][BMt][BK];
  __shared__ f16 Bs[2][BNt][BK];
  const int tid  = threadIdx.x;
  const int lane = tid & 63;
  const int w    = tid >> 6;
  const int wr   = w >> 1, wc = w & 1;

  const int gx = gridDim.x, nxy = gx * gridDim.y;
  int lin = blockIdx.y * gx + blockIdx.x;
  lin = (lin & 7) * (nxy >> 3) + (lin >> 3);
  const int m0 = (lin % gx) * BMt;
  const int n0 = (lin / gx) * BNt;

  f32x4 acc[MF][NF] = {};
  RegStage<BMt> ra;   // dead when TA == f16
  RegStage<BNt> rb;   // dead when TB == f16

  auto stage_issue = [&](int buf, int k0) {
    if constexpr (sizeof(TA) == 2)
      stage_f16<BMt>(As[buf], (const f16*)A + (size_t)m0 * lda + k0, lda, w, lane);
    else
      ra.load((const float*)A + (size_t)m0 * lda + k0, lda, tid);
    if constexpr (sizeof(TB) == 2)
      stage_f16<BNt>(Bs[buf], (const f16*)B + (size_t)n0 * ldb + k0, ldb, w, lane);
    else
      rb.load((const float*)B + (size_t)n0 * ldb + k0, ldb, tid);
  };
  auto stage_write = [&](int buf) {
    if constexpr (sizeof(TA) == 4) ra.write(As[buf], tid);
    if constexpr (sizeof(TB) == 4) rb.write(Bs[buf], tid);
  };
  auto compute = [&](int buf) {
    const int fr = lane & 15, q = lane >> 4;
#pragma unroll
    for (int kk = 0; kk < 2; kk++) {
      f16x8 af[MF], bf[NF];
#pragma unroll
      for (int i = 0; i < MF; i++) {
        const int r = wr * (BMt / 2) + i * 16 + fr;
        const int slot = (kk * 4 + q) ^ (r & 7);
        af[i] = *(const f16x8*)&As[buf][r][slot * 8];
      }
#pragma unroll
      for (int j = 0; j < NF; j++) {
        const int r = wc * (BNt / 2) + j * 16 + fr;
        const int slot = (kk * 4 + q) ^ (r & 7);
        bf[j] = *(const f16x8*)&Bs[buf][r][slot * 8];
      }
#pragma unroll
      for (int i = 0; i < MF; i++)
#pragma unroll
        for (int j = 0; j < NF; j++)
          acc[i][j] = __builtin_amdgcn_mfma_f32_16x16x32_f16(af[i], bf[j], acc[i][j], 0, 0, 0);
    }
  };

  stage_issue(0, 0);
  stage_write(0);
  __syncthreads();

  const int KT = K / BK;
  for (int kt = 0; kt < KT; kt++) {
    const int cur = kt & 1, nxt = cur ^ 1;
    if (kt + 1 < KT) stage_issue(nxt, (kt + 1) * BK);
    compute(cur);
    if (kt + 1 < KT) stage_write(nxt);
    __syncthreads();
  }

  const int fr = lane & 15;
  const int rg = (lane >> 4) << 2;
#pragma unroll
  for (int i = 0; i < MF; i++) {
#pragma unroll
    for (int j = 0; j < NF; j++) {
      const int col = n0 + wc * (BNt / 2) + j * 16 + fr;
      float bv = 0.f;
      if constexpr (BIAS) bv = bias[col];
#pragma unroll
      for (int r = 0; r < 4; r++) {
        const int row = m0 + wr * (BMt / 2) + i * 16 + rg + r;
        float v = acc[i][j][r] + bv;
        if constexpr (RELU) v = fmaxf(v, 0.f);
        C[(size_t)row * ldc + col] = (TC)v;
      }
    }
  }
}

// f32 -> fp16 vector copy (8 elems/thread)
__global__ __launch_bounds__(256)
void copy_f32_f16(const float* __restrict__ in, f16* __restrict__ o)
{
  const size_t i = ((size_t)blockIdx.x * 256 + threadIdx.x) * 8;
  const float4 a = ((const float4*)(in + i))[0];
  const float4 b = ((const float4*)(in + i))[1];
  f16x8 v;
  v[0] = (f16)a.x; v[1] = (f16)a.y; v[2] = (f16)a.z; v[3] = (f16)a.w;
  v[4] = (f16)b.x; v[5] = (f16)b.y; v[6] = (f16)b.z; v[7] = (f16)b.w;
  *(f16x8*)(o + i) = v;
}

// bT[row] = dot(x1[row, :1024], bias)  (exact f32)
__global__ __launch_bounds__(256)
void bias_dot(const float* __restrict__ x1, const float* __restrict__ bias,
              float* __restrict__ bT)
{
  const int row  = blockIdx.x * 4 + (threadIdx.x >> 6);
  const int lane = threadIdx.x & 63;
  const float4* r = (const float4*)(x1 + (size_t)row * 1024);
  const float4* bb = (const float4*)bias;
  float acc = 0.f;
#pragma unroll
  for (int j = 0; j < 4; j++) {
    const float4 a = r[lane + j * 64];
    const float4 b = bb[lane + j * 64];
    acc += a.x * b.x + a.y * b.y + a.z * b.z + a.w * b.w;
  }
#pragma unroll
  for (int off = 32; off > 0; off >>= 1) acc += __shfl_xor(acc, off);
  if (lane == 0) bT[row] = acc;
}

// ---------------------------------------------------------------------------
// Row softmax over 2048 f32 scores; writes P fp16 packed into first 4KB of row.
// (R5-proven: per-row ownership -> in-place is race-free.)
// ---------------------------------------------------------------------------
__global__ __launch_bounds__(256)
void softmax_rows(float* __restrict__ S)
{
  float* row = S + (size_t)blockIdx.x * 2048;
  const int t = threadIdx.x;
  const float4 v0 = ((const float4*)row)[t];
  const float4 v1 = ((const float4*)row)[t + 256];

  float m = fmaxf(fmaxf(fmaxf(v0.x, v0.y), fmaxf(v0.z, v0.w)),
                  fmaxf(fmaxf(v1.x, v1.y), fmaxf(v1.z, v1.w)));
#pragma unroll
  for (int off = 32; off > 0; off >>= 1) m = fmaxf(m, __shfl_xor(m, off));
  __shared__ float red[8];
  if ((t & 63) == 0) red[t >> 6] = m;
  __syncthreads();
  m = fmaxf(fmaxf(red[0], red[1]), fmaxf(red[2], red[3]));

  float e0 = __expf(v0.x - m), e1 = __expf(v0.y - m), e2 = __expf(v0.z - m), e3 = __expf(v0.w - m);
  float e4 = __expf(v1.x - m), e5 = __expf(v1.y - m), e6 = __expf(v1.z - m), e7 = __expf(v1.w - m);
  float s = ((e0 + e1) + (e2 + e3)) + ((e4 + e5) + (e6 + e7));
#pragma unroll
  for (int off = 32; off > 0; off >>= 1) s += __shfl_xor(s, off);
  if ((t & 63) == 0) red[4 + (t >> 6)] = s;
  __syncthreads();
  const float inv = 1.f / (red[4] + red[5] + red[6] + red[7]);

  f16x4 o0, o1;
  o0[0] = (f16)(e0 * inv); o0[1] = (f16)(e1 * inv); o0[2] = (f16)(e2 * inv); o0[3] = (f16)(e3 * inv);
  o1[0] = (f16)(e4 * inv); o1[1] = (f16)(e5 * inv); o1[2] = (f16)(e6 * inv); o1[3] = (f16)(e7 * inv);
  f16x4* orow = (f16x4*)row;
  orow[t]       = o0;
  orow[t + 256] = o1;
}

// ---------------------------------------------------------------------------
extern "C" void kernel_launch(void* const* d_in, const int* in_sizes, int n_in,
                              void* d_out, int out_size, void* d_ws, size_t ws_size,
                              hipStream_t stream)
{
  const float* x1   = (const float*)d_in[0];
  const float* x2   = (const float*)d_in[1];
  const float* U    = (const float*)d_in[2];
  const float* bias = (const float*)d_in[3];
  const float* fcw  = (const float*)d_in[4];
  const float* fcb  = (const float*)d_in[5];
  float* out = (float*)d_out;

  const int S = 2048, D = 1024, E = 512, B = 8;
  const size_t MB = 1ull << 20;
  const size_t KB64 = 64 * 1024;

  // FULL layout:  W2 4MB | bT 64KB | Sb 16MB                  = 20.06 MB
  //   (W1T lives in the dead second halves of Sb rows 0..511 after softmax)
  // FALLBACK:     W2 4MB | W1T 2MB | bT 64KB | Sb 8MB | Uh | Fh = 17.06 MB
  const bool FULL = ws_size >= (4 * MB + KB64 + 16 * MB);   // 21,037,056 B

  char* w = (char*)d_ws;
  f16*   W2  = (f16*)(w);
  f16*   W1Tf = (f16*)(w + 4 * MB);                 // fallback only
  float* bT  = FULL ? (float*)(w + 4 * MB) : (float*)(w + 6 * MB);
  float* Sb  = FULL ? (float*)(w + 4 * MB + KB64) : (float*)(w + 6 * MB + KB64);
  f16*   Uh  = (f16*)(w + 14 * MB + KB64);          // fallback only
  f16*   Fh  = (f16*)(w + 16 * MB + KB64);          // fallback only

  const int SC = FULL ? 2048 : 1024;

  // X2h_all overlays d_out exactly (row s of out[b] aliases row s of X2h[b]).
  // K4' writes out[b] only AFTER K2 of batch b consumed X2h[b] (stream-ordered).
  f16* X2h = (f16*)d_out;

  copy_f32_f16<<<dim3(B * S * D / 2048), 256, 0, stream>>>(x2, X2h);
  bias_dot<<<dim3(B * S / 4), 256, 0, stream>>>(x1, bias, bT);
  if (!FULL) {
    copy_f32_f16<<<dim3(D * D / 2048), 256, 0, stream>>>(U, Uh);
    copy_f32_f16<<<dim3(E * D / 2048), 256, 0, stream>>>(fcw, Fh);
  }

  for (int b = 0; b < B; b++) {
    const float* x1b = x1 + (size_t)b * S * D;
    const f16*   X2b = X2h + (size_t)b * S * D;

    if (FULL) {
      // K0: W2[t][d] = sum_e x1b[t,e] U[d,e]  (both f32 reg-stage)  grid (32,8)
      gemm_tn<64, 128, float, float, false, false, f16><<<dim3(S / 64, D / 128), 256, 0, stream>>>(
          x1b, D, U, D, W2, D, nullptr, D);

      // K2 full: Sb[s][t] = sum_d X2b[s,d] W2[t,d] + bT[t]  grid (32,16)=512
      gemm_tn<64, 128, f16, f16, true, false, float><<<dim3(S / 64, S / 128), 256, 0, stream>>>(
          X2b, D, W2, D, Sb, S, bT + (size_t)b * S, D);

      // softmax all rows (reads full f32 rows -> MUST precede W1T tail-writes)
      softmax_rows<<<dim3(S), 256, 0, stream>>>(Sb);

      // W1T into Sb row-tails: C[e][t] at (f16*)Sb + e*4096 + 2048 + t
      gemm_tn<64, 128, float, float, false, false, f16><<<dim3(E / 64, S / 128), 256, 0, stream>>>(
          fcw, D, x1b, D, (f16*)Sb + 2048, 2 * S, nullptr, D);

      // K4': out[b] = relu(P @ W1T^T + fcb); A=P (lda 4096), B=tails (ldb 4096)
      gemm_tn<64, 64, f16, f16, true, true, float><<<dim3(S / 64, E / 64), 256, 0, stream>>>(
          (const f16*)Sb, 2 * S, (const f16*)Sb + 2048, 2 * S,
          out + (size_t)b * S * E, E, fcb, S);
    } else {
      // K0: W2 = x1b @ Uh^T  grid (32,8)
      gemm_tn<64, 128, float, f16, false, false, f16><<<dim3(S / 64, D / 128), 256, 0, stream>>>(
          x1b, D, Uh, D, W2, D, nullptr, D);

      // W1T[e][t] = sum_d Fh[e,d] x1b[t,d]  grid (8,32)
      gemm_tn<64, 64, f16, float, false, false, f16><<<dim3(E / 64, S / 64), 256, 0, stream>>>(
          Fh, D, x1b, D, W1Tf, S, nullptr, D);

      for (int s0 = 0; s0 < S; s0 += SC) {
        gemm_tn<64, 128, f16, f16, true, false, float><<<dim3(SC / 64, S / 128), 256, 0, stream>>>(
            X2b + (size_t)s0 * D, D, W2, D, Sb, S, bT + (size_t)b * S, D);
        softmax_rows<<<dim3(SC), 256, 0, stream>>>(Sb);
        gemm_tn<64, 64, f16, f16, true, true, float><<<dim3(SC / 64, E / 64), 256, 0, stream>>>(
            (const f16*)Sb, 2 * S, W1Tf, S, out + ((size_t)b * S + s0) * E, E, fcb, S);
      }
    }
  }
}

// Round 13
// 791.493 us; speedup vs baseline: 1.0432x; 1.0432x over previous
//
#include <hip/hip_runtime.h>
#include <hip/hip_fp16.h>
#include <cstddef>
#include <cstdint>

typedef _Float16 f16;
typedef _Float16 f16x8 __attribute__((ext_vector_type(8)));
typedef _Float16 f16x4 __attribute__((ext_vector_type(4)));
typedef float    f32x4 __attribute__((ext_vector_type(4)));

#define BK 64   // K-tile depth (fp16 elems); 2 MFMA k-steps per tile

// async 16B global->LDS (linear LDS dest = wave-uniform base + lane*16)
__device__ __forceinline__ void gload16(const void* g, void* lds) {
  __builtin_amdgcn_global_load_lds(
      (const __attribute__((address_space(1))) unsigned int*)g,
      (__attribute__((address_space(3))) unsigned int*)lds, 16, 0, 0);
}

// Stage an [R x 64] fp16 tile via global_load_lds (array form, proven core).
template<int R>
__device__ __forceinline__ void stage_f16(f16 (*buf)[BK], const f16* __restrict__ src,
                                          int ld, int w, int lane) {
#pragma unroll
  for (int i = 0; i < R / 32; i++) {
    const int grp  = w * (R / 32) + i;          // wave-uniform
    const int r    = grp * 8 + (lane >> 3);
    const int slot = (lane & 7) ^ (r & 7);
    gload16(src + (size_t)r * ld + slot * 8, &buf[grp * 8][0]);
  }
}

// Pointer form for the fused kernel (same layout/swizzle).
template<int R>
__device__ __forceinline__ void stage_f16p(f16* buf, const f16* __restrict__ src,
                                           int ld, int w, int lane) {
#pragma unroll
  for (int i = 0; i < R / 32; i++) {
    const int grp  = w * (R / 32) + i;
    const int r    = grp * 8 + (lane >> 3);
    const int slot = (lane & 7) ^ (r & 7);
    gload16(src + (size_t)r * ld + slot * 8, buf + (size_t)grp * 8 * BK);
  }
}

// Reg-staging for f32 sources (T14 issue-early / write-late).
template<int R>
struct RegStage {
  static constexpr int NV = (R == 128) ? 8 : 4;
  float4 v[NV];
  __device__ __forceinline__ void load(const float* __restrict__ src, int ld, int tid) {
    const int r = (R == 128) ? (tid >> 1) : (tid >> 2);
    const int h = (R == 128) ? (tid & 1) * 32 : (tid & 3) * 16;
    const float* p = src + (size_t)r * ld + h;
#pragma unroll
    for (int j = 0; j < NV; j++) v[j] = ((const float4*)p)[j];
  }
  __device__ __forceinline__ void write(f16* buf, int tid) {
    const int r = (R == 128) ? (tid >> 1) : (tid >> 2);
    const int h = (R == 128) ? (tid & 1) * 32 : (tid & 3) * 16;
#pragma unroll
    for (int g = 0; g < NV / 2; g++) {
      const float4 a = v[g * 2], b = v[g * 2 + 1];
      f16x8 o;
      o[0] = (f16)a.x; o[1] = (f16)a.y; o[2] = (f16)a.z; o[3] = (f16)a.w;
      o[4] = (f16)b.x; o[5] = (f16)b.y; o[6] = (f16)b.z; o[7] = (f16)b.w;
      const int slot = (h / 8 + g) ^ (r & 7);
      *(f16x8*)(buf + r * BK + slot * 8) = o;
    }
  }
};

// ---------------------------------------------------------------------------
// Device-side TN GEMM tile body (mechanical refactor of the proven core).
// smem: [2][BMt][BK] As | [2][BNt][BK] Bs (f16).
// ---------------------------------------------------------------------------
template<int BMt, int BNt, typename TA, typename TB, bool BIAS, bool RELU, typename TC>
__device__ __forceinline__ void gemm_body(char* smem, int lin0, int gx, int nxy,
                                          const TA* __restrict__ A, int lda,
                                          const TB* __restrict__ B, int ldb,
                                          TC* __restrict__ C, int ldc,
                                          const float* __restrict__ bias, int K)
{
  constexpr int MF = BMt / 32;
  constexpr int NF = BNt / 32;
  f16* AsB = (f16*)smem;
  f16* BsB = AsB + 2 * BMt * BK;
  const int tid  = threadIdx.x;
  const int lane = tid & 63;
  const int w    = tid >> 6;
  const int wr   = w >> 1, wc = w & 1;

  int lin = (lin0 & 7) * (nxy >> 3) + (lin0 >> 3);
  const int m0 = (lin % gx) * BMt;
  const int n0 = (lin / gx) * BNt;

  f32x4 acc[MF][NF] = {};
  RegStage<BMt> ra;   // dead when TA == f16
  RegStage<BNt> rb;   // dead when TB == f16

  auto stage_issue = [&](int buf, int k0) {
    if constexpr (sizeof(TA) == 2)
      stage_f16p<BMt>(AsB + buf * BMt * BK, (const f16*)A + (size_t)m0 * lda + k0, lda, w, lane);
    else
      ra.load((const float*)A + (size_t)m0 * lda + k0, lda, tid);
    if constexpr (sizeof(TB) == 2)
      stage_f16p<BNt>(BsB + buf * BNt * BK, (const f16*)B + (size_t)n0 * ldb + k0, ldb, w, lane);
    else
      rb.load((const float*)B + (size_t)n0 * ldb + k0, ldb, tid);
  };
  auto stage_write = [&](int buf) {
    if constexpr (sizeof(TA) == 4) ra.write(AsB + buf * BMt * BK, tid);
    if constexpr (sizeof(TB) == 4) rb.write(BsB + buf * BNt * BK, tid);
  };
  auto compute = [&](int buf) {
    const int fr = lane & 15, q = lane >> 4;
#pragma unroll
    for (int kk = 0; kk < 2; kk++) {
      f16x8 af[MF], bf[NF];
#pragma unroll
      for (int i = 0; i < MF; i++) {
        const int r = wr * (BMt / 2) + i * 16 + fr;
        const int slot = (kk * 4 + q) ^ (r & 7);
        af[i] = *(const f16x8*)(AsB + (buf * BMt + r) * BK + slot * 8);
      }
#pragma unroll
      for (int j = 0; j < NF; j++) {
        const int r = wc * (BNt / 2) + j * 16 + fr;
        const int slot = (kk * 4 + q) ^ (r & 7);
        bf[j] = *(const f16x8*)(BsB + (buf * BNt + r) * BK + slot * 8);
      }
#pragma unroll
      for (int i = 0; i < MF; i++)
#pragma unroll
        for (int j = 0; j < NF; j++)
          acc[i][j] = __builtin_amdgcn_mfma_f32_16x16x32_f16(af[i], bf[j], acc[i][j], 0, 0, 0);
    }
  };

  stage_issue(0, 0);
  stage_write(0);
  __syncthreads();

  const int KT = K / BK;
  for (int kt = 0; kt < KT; kt++) {
    const int cur = kt & 1, nxt = cur ^ 1;
    if (kt + 1 < KT) stage_issue(nxt, (kt + 1) * BK);
    compute(cur);
    if (kt + 1 < KT) stage_write(nxt);
    __syncthreads();
  }

  const int fr = lane & 15;
  const int rg = (lane >> 4) << 2;
#pragma unroll
  for (int i = 0; i < MF; i++) {
#pragma unroll
    for (int j = 0; j < NF; j++) {
      const int col = n0 + wc * (BNt / 2) + j * 16 + fr;
      float bv = 0.f;
      if constexpr (BIAS) bv = bias[col];
#pragma unroll
      for (int r = 0; r < 4; r++) {
        const int row = m0 + wr * (BMt / 2) + i * 16 + rg + r;
        float v = acc[i][j][r] + bv;
        if constexpr (RELU) v = fmaxf(v, 0.f);
        C[(size_t)row * ldc + col] = (TC)v;
      }
    }
  }
}

// ---------------------------------------------------------------------------
// Standalone TN GEMM (champion, unchanged) — used for K2 and K4'.
// ---------------------------------------------------------------------------
template<int BMt, int BNt, typename TA, typename TB, bool BIAS, bool RELU, typename TC>
__global__ __launch_bounds__(256, 2)
void gemm_tn(const TA* __restrict__ A, int lda,
             const TB* __restrict__ B, int ldb,
             TC* __restrict__ C, int ldc,
             const float* __restrict__ bias, int K)
{
  __shared__ __align__(16) char smem[2 * (BMt + BNt) * BK * 2];
  const int nxy = gridDim.x * gridDim.y;
  gemm_body<BMt, BNt, TA, TB, BIAS, RELU, TC>(
      smem, blockIdx.y * gridDim.x + blockIdx.x, gridDim.x, nxy,
      A, lda, B, ldb, C, ldc, bias, K);
}

// ---------------------------------------------------------------------------
// Fused phase A: blocks 0..255 -> K0 tile (W2 = x1b @ Uh^T, 64x128 tiles);
// blocks 256..511 -> W1T tile (Fh @ x1b^T, 64x64 tiles). Independent outputs.
// ---------------------------------------------------------------------------
__global__ __launch_bounds__(256, 2)
void k0w1t(const float* __restrict__ x1b, const f16* __restrict__ Uh,
           const f16* __restrict__ Fh, f16* __restrict__ W2,
           f16* __restrict__ W1T)
{
  __shared__ __align__(16) char smem[2 * (64 + 128) * BK * 2];   // 48 KB
  const int blk = blockIdx.x;
  if (blk < 256)
    gemm_body<64, 128, float, f16, false, false, f16>(
        smem, blk, 32, 256, x1b, 1024, Uh, 1024, W2, 1024, nullptr, 1024);
  else
    gemm_body<64, 64, f16, float, false, false, f16>(
        smem, blk - 256, 8, 256, Fh, 1024, x1b, 1024, W1T, 2048, nullptr, 1024);
}

// f32 -> fp16 vector copy (8 elems/thread)
__global__ __launch_bounds__(256)
void copy_f32_f16(const float* __restrict__ in, f16* __restrict__ o)
{
  const size_t i = ((size_t)blockIdx.x * 256 + threadIdx.x) * 8;
  const float4 a = ((const float4*)(in + i))[0];
  const float4 b = ((const float4*)(in + i))[1];
  f16x8 v;
  v[0] = (f16)a.x; v[1] = (f16)a.y; v[2] = (f16)a.z; v[3] = (f16)a.w;
  v[4] = (f16)b.x; v[5] = (f16)b.y; v[6] = (f16)b.z; v[7] = (f16)b.w;
  *(f16x8*)(o + i) = v;
}

// prep: blocks 0..4095 -> bT[row]=x1[row,:].bias ; 4096..4863 -> U/fcw -> f16
__global__ __launch_bounds__(256)
void prep(const float* __restrict__ x1, const float* __restrict__ bias,
          float* __restrict__ bT, const float* __restrict__ U,
          const float* __restrict__ fcw, f16* __restrict__ Uh,
          f16* __restrict__ Fh)
{
  if (blockIdx.x < 4096) {
    const int row  = blockIdx.x * 4 + (threadIdx.x >> 6);
    const int lane = threadIdx.x & 63;
    const float4* r = (const float4*)(x1 + (size_t)row * 1024);
    const float4* bb = (const float4*)bias;
    float acc = 0.f;
#pragma unroll
    for (int j = 0; j < 4; j++) {
      const float4 a = r[lane + j * 64];
      const float4 b = bb[lane + j * 64];
      acc += a.x * b.x + a.y * b.y + a.z * b.z + a.w * b.w;
    }
#pragma unroll
    for (int off = 32; off > 0; off >>= 1) acc += __shfl_xor(acc, off);
    if (lane == 0) bT[row] = acc;
  } else {
    const int bi = blockIdx.x - 4096;
    const bool isU = bi < 512;
    const size_t base = (size_t)(isU ? bi : bi - 512) * 2048;
    const float* in = (isU ? U : fcw) + base;
    f16* o = (isU ? Uh : Fh) + base;
    const size_t i = (size_t)threadIdx.x * 8;
    const float4 a = ((const float4*)(in + i))[0];
    const float4 b = ((const float4*)(in + i))[1];
    f16x8 v;
    v[0] = (f16)a.x; v[1] = (f16)a.y; v[2] = (f16)a.z; v[3] = (f16)a.w;
    v[4] = (f16)b.x; v[5] = (f16)b.y; v[6] = (f16)b.z; v[7] = (f16)b.w;
    *(f16x8*)(o + i) = v;
  }
}

// ---------------------------------------------------------------------------
// Row softmax over 2048 f32 scores; writes P fp16 packed into first 4KB of row.
// ---------------------------------------------------------------------------
__global__ __launch_bounds__(256)
void softmax_rows(float* __restrict__ S)
{
  float* row = S + (size_t)blockIdx.x * 2048;
  const int t = threadIdx.x;
  const float4 v0 = ((const float4*)row)[t];
  const float4 v1 = ((const float4*)row)[t + 256];

  float m = fmaxf(fmaxf(fmaxf(v0.x, v0.y), fmaxf(v0.z, v0.w)),
                  fmaxf(fmaxf(v1.x, v1.y), fmaxf(v1.z, v1.w)));
#pragma unroll
  for (int off = 32; off > 0; off >>= 1) m = fmaxf(m, __shfl_xor(m, off));
  __shared__ float red[8];
  if ((t & 63) == 0) red[t >> 6] = m;
  __syncthreads();
  m = fmaxf(fmaxf(red[0], red[1]), fmaxf(red[2], red[3]));

  float e0 = __expf(v0.x - m), e1 = __expf(v0.y - m), e2 = __expf(v0.z - m), e3 = __expf(v0.w - m);
  float e4 = __expf(v1.x - m), e5 = __expf(v1.y - m), e6 = __expf(v1.z - m), e7 = __expf(v1.w - m);
  float s = ((e0 + e1) + (e2 + e3)) + ((e4 + e5) + (e6 + e7));
#pragma unroll
  for (int off = 32; off > 0; off >>= 1) s += __shfl_xor(s, off);
  if ((t & 63) == 0) red[4 + (t >> 6)] = s;
  __syncthreads();
  const float inv = 1.f / (red[4] + red[5] + red[6] + red[7]);

  f16x4 o0, o1;
  o0[0] = (f16)(e0 * inv); o0[1] = (f16)(e1 * inv); o0[2] = (f16)(e2 * inv); o0[3] = (f16)(e3 * inv);
  o1[0] = (f16)(e4 * inv); o1[1] = (f16)(e5 * inv); o1[2] = (f16)(e6 * inv); o1[3] = (f16)(e7 * inv);
  f16x4* orow = (f16x4*)row;
  orow[t]       = o0;
  orow[t + 256] = o1;
}

// ---------------------------------------------------------------------------
extern "C" void kernel_launch(void* const* d_in, const int* in_sizes, int n_in,
                              void* d_out, int out_size, void* d_ws, size_t ws_size,
                              hipStream_t stream)
{
  const float* x1   = (const float*)d_in[0];
  const float* x2   = (const float*)d_in[1];
  const float* U    = (const float*)d_in[2];
  const float* bias = (const float*)d_in[3];
  const float* fcw  = (const float*)d_in[4];
  const float* fcb  = (const float*)d_in[5];
  float* out = (float*)d_out;

  const int S = 2048, D = 1024, E = 512, B = 8;
  const int SC = 1024;
  const size_t MB = 1ull << 20;
  const size_t KB64 = 64 * 1024;

  // ws (proven 17.06 MB): W2 4 | W1T 2 | bT 64K | Sb 8 | Uh 2 | Fh 1
  char* w = (char*)d_ws;
  f16*   W2  = (f16*)(w);
  f16*   W1T = (f16*)(w + 4 * MB);
  float* bT  = (float*)(w + 6 * MB);
  float* Sb  = (float*)(w + 6 * MB + KB64);
  f16*   Uh  = (f16*)(w + 14 * MB + KB64);
  f16*   Fh  = (f16*)(w + 16 * MB + KB64);

  // X2h_all overlays d_out exactly (row s of out[b] aliases row s of X2h[b]).
  // K4' writes out[b] rows only AFTER K2 consumed them (stream-ordered).
  f16* X2h = (f16*)d_out;

  copy_f32_f16<<<dim3(B * S * D / 2048), 256, 0, stream>>>(x2, X2h);
  prep<<<dim3(4864), 256, 0, stream>>>(x1, bias, bT, U, fcw, Uh, Fh);

  for (int b = 0; b < B; b++) {
    const float* x1b = x1 + (size_t)b * S * D;
    const f16*   X2b = X2h + (size_t)b * S * D;

    // Fused phase A: K0 (blocks 0..255) + W1T (256..511), 2 blocks/CU
    k0w1t<<<dim3(512), 256, 0, stream>>>(x1b, Uh, Fh, W2, W1T);

    for (int s0 = 0; s0 < S; s0 += SC) {
      // K2: Sb[s][t] = sum_d X2b[s0+s,d] W2[t,d] + bT[t]  grid (16,16)=256
      gemm_tn<64, 128, f16, f16, true, false, float><<<dim3(SC / 64, S / 128), 256, 0, stream>>>(
          X2b + (size_t)s0 * D, D, W2, D, Sb, S, bT + (size_t)b * S, D);
      // softmax -> P fp16 packed in-place (lda 2S)
      softmax_rows<<<dim3(SC), 256, 0, stream>>>(Sb);
      // K4': out rows [s0,s0+SC) = relu(P @ W1T^T + fcb)  (K=t=2048) grid (16,8)=128
      gemm_tn<64, 64, f16, f16, true, true, float><<<dim3(SC / 64, E / 64), 256, 0, stream>>>(
          (const f16*)Sb, 2 * S, W1T, S, out + ((size_t)b * S + s0) * E, E, fcb, S);
    }
  }
}

// Round 15
// 721.467 us; speedup vs baseline: 1.1444x; 1.0971x over previous
//
#include <hip/hip_runtime.h>
#include <hip/hip_fp16.h>
#include <cstddef>
#include <cstdint>

typedef _Float16 f16;
typedef _Float16 f16x8 __attribute__((ext_vector_type(8)));
typedef _Float16 f16x4 __attribute__((ext_vector_type(4)));
typedef float    f32x4 __attribute__((ext_vector_type(4)));

#define BK 64   // K-tile depth (fp16 elems); 2 MFMA k-steps per tile

// async 16B global->LDS (linear LDS dest = wave-uniform base + lane*16)
__device__ __forceinline__ void gload16(const void* g, void* lds) {
  __builtin_amdgcn_global_load_lds(
      (const __attribute__((address_space(1))) unsigned int*)g,
      (__attribute__((address_space(3))) unsigned int*)lds, 16, 0, 0);
}

// Stage an [R x 64] fp16 tile via global_load_lds. LDS row r holds global
// 8-elem slot s at slot s^(r&7) (rule-21 both-sides swizzle).
template<int R>
__device__ __forceinline__ void stage_f16(f16 (*buf)[BK], const f16* __restrict__ src,
                                          int ld, int w, int lane) {
#pragma unroll
  for (int i = 0; i < R / 32; i++) {
    const int grp  = w * (R / 32) + i;          // wave-uniform
    const int r    = grp * 8 + (lane >> 3);
    const int slot = (lane & 7) ^ (r & 7);
    gload16(src + (size_t)r * ld + slot * 8, &buf[grp * 8][0]);
  }
}

// Reg-staging for f32 sources (T14 issue-early / write-late).
template<int R>
struct RegStage {
  static constexpr int NV = (R == 128) ? 8 : 4;
  float4 v[NV];
  __device__ __forceinline__ void load(const float* __restrict__ src, int ld, int tid) {
    const int r = (R == 128) ? (tid >> 1) : (tid >> 2);
    const int h = (R == 128) ? (tid & 1) * 32 : (tid & 3) * 16;
    const float* p = src + (size_t)r * ld + h;
#pragma unroll
    for (int j = 0; j < NV; j++) v[j] = ((const float4*)p)[j];
  }
  __device__ __forceinline__ void write(f16 (*buf)[BK], int tid) {
    const int r = (R == 128) ? (tid >> 1) : (tid >> 2);
    const int h = (R == 128) ? (tid & 1) * 32 : (tid & 3) * 16;
#pragma unroll
    for (int g = 0; g < NV / 2; g++) {
      const float4 a = v[g * 2], b = v[g * 2 + 1];
      f16x8 o;
      o[0] = (f16)a.x; o[1] = (f16)a.y; o[2] = (f16)a.z; o[3] = (f16)a.w;
      o[4] = (f16)b.x; o[5] = (f16)b.y; o[6] = (f16)b.z; o[7] = (f16)b.w;
      const int slot = (h / 8 + g) ^ (r & 7);
      *(f16x8*)&buf[r][slot * 8] = o;
    }
  }
};

// ---------------------------------------------------------------------------
// TN GEMM, double-buffered (proven core): C = A@B^T (+bias[n]) (+relu).
// fp16 operands: global_load_lds. f32 operands: reg-stage + cvt.
// Chunked bijective XCD swizzle on (bx,by); requires nxy % 8 == 0.
// ---------------------------------------------------------------------------
template<int BMt, int BNt, typename TA, typename TB, bool BIAS, bool RELU, typename TC>
__global__ __launch_bounds__(256, 2)
void gemm_tn(const TA* __restrict__ A, int lda,
             const TB* __restrict__ B, int ldb,
             TC* __restrict__ C, int ldc,
             const float* __restrict__ bias, int K)
{
  constexpr int MF = BMt / 32;
  constexpr int NF = BNt / 32;
  __shared__ f16 As[2][BMt][BK];
  __shared__ f16 Bs[2][BNt][BK];
  const int tid  = threadIdx.x;
  const int lane = tid & 63;
  const int w    = tid >> 6;
  const int wr   = w >> 1, wc = w & 1;

  const int gx = gridDim.x, nxy = gx * gridDim.y;
  int lin = blockIdx.y * gx + blockIdx.x;
  lin = (lin & 7) * (nxy >> 3) + (lin >> 3);
  const int m0 = (lin % gx) * BMt;
  const int n0 = (lin / gx) * BNt;

  f32x4 acc[MF][NF] = {};
  RegStage<BMt> ra;   // dead when TA == f16
  RegStage<BNt> rb;   // dead when TB == f16

  auto stage_issue = [&](int buf, int k0) {
    if constexpr (sizeof(TA) == 2)
      stage_f16<BMt>(As[buf], (const f16*)A + (size_t)m0 * lda + k0, lda, w, lane);
    else
      ra.load((const float*)A + (size_t)m0 * lda + k0, lda, tid);
    if constexpr (sizeof(TB) == 2)
      stage_f16<BNt>(Bs[buf], (const f16*)B + (size_t)n0 * ldb + k0, ldb, w, lane);
    else
      rb.load((const float*)B + (size_t)n0 * ldb + k0, ldb, tid);
  };
  auto stage_write = [&](int buf) {
    if constexpr (sizeof(TA) == 4) ra.write(As[buf], tid);
    if constexpr (sizeof(TB) == 4) rb.write(Bs[buf], tid);
  };
  auto compute = [&](int buf) {
    const int fr = lane & 15, q = lane >> 4;
#pragma unroll
    for (int kk = 0; kk < 2; kk++) {
      f16x8 af[MF], bf[NF];
#pragma unroll
      for (int i = 0; i < MF; i++) {
        const int r = wr * (BMt / 2) + i * 16 + fr;
        const int slot = (kk * 4 + q) ^ (r & 7);
        af[i] = *(const f16x8*)&As[buf][r][slot * 8];
      }
#pragma unroll
      for (int j = 0; j < NF; j++) {
        const int r = wc * (BNt / 2) + j * 16 + fr;
        const int slot = (kk * 4 + q) ^ (r & 7);
        bf[j] = *(const f16x8*)&Bs[buf][r][slot * 8];
      }
#pragma unroll
      for (int i = 0; i < MF; i++)
#pragma unroll
        for (int j = 0; j < NF; j++)
          acc[i][j] = __builtin_amdgcn_mfma_f32_16x16x32_f16(af[i], bf[j], acc[i][j], 0, 0, 0);
    }
  };

  stage_issue(0, 0);
  stage_write(0);
  __syncthreads();

  const int KT = K / BK;
  for (int kt = 0; kt < KT; kt++) {
    const int cur = kt & 1, nxt = cur ^ 1;
    if (kt + 1 < KT) stage_issue(nxt, (kt + 1) * BK);
    compute(cur);
    if (kt + 1 < KT) stage_write(nxt);
    __syncthreads();
  }

  const int fr = lane & 15;
  const int rg = (lane >> 4) << 2;
#pragma unroll
  for (int i = 0; i < MF; i++) {
#pragma unroll
    for (int j = 0; j < NF; j++) {
      const int col = n0 + wc * (BNt / 2) + j * 16 + fr;
      float bv = 0.f;
      if constexpr (BIAS) bv = bias[col];
#pragma unroll
      for (int r = 0; r < 4; r++) {
        const int row = m0 + wr * (BMt / 2) + i * 16 + rg + r;
        float v = acc[i][j][r] + bv;
        if constexpr (RELU) v = fmaxf(v, 0.f);
        C[(size_t)row * ldc + col] = (TC)v;
      }
    }
  }
}

// f32 -> fp16 vector copy (8 elems/thread)
__global__ __launch_bounds__(256)
void copy_f32_f16(const float* __restrict__ in, f16* __restrict__ o)
{
  const size_t i = ((size_t)blockIdx.x * 256 + threadIdx.x) * 8;
  const float4 a = ((const float4*)(in + i))[0];
  const float4 b = ((const float4*)(in + i))[1];
  f16x8 v;
  v[0] = (f16)a.x; v[1] = (f16)a.y; v[2] = (f16)a.z; v[3] = (f16)a.w;
  v[4] = (f16)b.x; v[5] = (f16)b.y; v[6] = (f16)b.z; v[7] = (f16)b.w;
  *(f16x8*)(o + i) = v;
}

// merged U->Uh (blocks 0..511) and fcw->Fh (blocks 512..767).
// Launch with grid 512 to convert U only.
__global__ __launch_bounds__(256)
void copy_uf(const float* __restrict__ U, const float* __restrict__ fcw,
             f16* __restrict__ Uh, f16* __restrict__ Fh)
{
  const bool isU = blockIdx.x < 512;
  const size_t base = (size_t)(isU ? blockIdx.x : blockIdx.x - 512) * 2048;
  const float* in = (isU ? U : fcw) + base;
  f16* o = (isU ? Uh : Fh) + base;
  const size_t i = (size_t)threadIdx.x * 8;
  const float4 a = ((const float4*)(in + i))[0];
  const float4 b = ((const float4*)(in + i))[1];
  f16x8 v;
  v[0] = (f16)a.x; v[1] = (f16)a.y; v[2] = (f16)a.z; v[3] = (f16)a.w;
  v[4] = (f16)b.x; v[5] = (f16)b.y; v[6] = (f16)b.z; v[7] = (f16)b.w;
  *(f16x8*)(o + i) = v;
}

// bT[row] = dot(x1[row, :1024], bias)  (exact f32)
__global__ __launch_bounds__(256)
void bias_dot(const float* __restrict__ x1, const float* __restrict__ bias,
              float* __restrict__ bT)
{
  const int row  = blockIdx.x * 4 + (threadIdx.x >> 6);
  const int lane = threadIdx.x & 63;
  const float4* r = (const float4*)(x1 + (size_t)row * 1024);
  const float4* bb = (const float4*)bias;
  float acc = 0.f;
#pragma unroll
  for (int j = 0; j < 4; j++) {
    const float4 a = r[lane + j * 64];
    const float4 b = bb[lane + j * 64];
    acc += a.x * b.x + a.y * b.y + a.z * b.z + a.w * b.w;
  }
#pragma unroll
  for (int off = 32; off > 0; off >>= 1) acc += __shfl_xor(acc, off);
  if (lane == 0) bT[row] = acc;
}

// ---------------------------------------------------------------------------
// Row softmax over 2048 f32 scores; writes P fp16 packed into first 4KB of row.
// ---------------------------------------------------------------------------
__global__ __launch_bounds__(256)
void softmax_rows(float* __restrict__ S)
{
  float* row = S + (size_t)blockIdx.x * 2048;
  const int t = threadIdx.x;
  const float4 v0 = ((const float4*)row)[t];
  const float4 v1 = ((const float4*)row)[t + 256];

  float m = fmaxf(fmaxf(fmaxf(v0.x, v0.y), fmaxf(v0.z, v0.w)),
                  fmaxf(fmaxf(v1.x, v1.y), fmaxf(v1.z, v1.w)));
#pragma unroll
  for (int off = 32; off > 0; off >>= 1) m = fmaxf(m, __shfl_xor(m, off));
  __shared__ float red[8];
  if ((t & 63) == 0) red[t >> 6] = m;
  __syncthreads();
  m = fmaxf(fmaxf(red[0], red[1]), fmaxf(red[2], red[3]));

  float e0 = __expf(v0.x - m), e1 = __expf(v0.y - m), e2 = __expf(v0.z - m), e3 = __expf(v0.w - m);
  float e4 = __expf(v1.x - m), e5 = __expf(v1.y - m), e6 = __expf(v1.z - m), e7 = __expf(v1.w - m);
  float s = ((e0 + e1) + (e2 + e3)) + ((e4 + e5) + (e6 + e7));
#pragma unroll
  for (int off = 32; off > 0; off >>= 1) s += __shfl_xor(s, off);
  if ((t & 63) == 0) red[4 + (t >> 6)] = s;
  __syncthreads();
  const float inv = 1.f / (red[4] + red[5] + red[6] + red[7]);

  f16x4 o0, o1;
  o0[0] = (f16)(e0 * inv); o0[1] = (f16)(e1 * inv); o0[2] = (f16)(e2 * inv); o0[3] = (f16)(e3 * inv);
  o1[0] = (f16)(e4 * inv); o1[1] = (f16)(e5 * inv); o1[2] = (f16)(e6 * inv); o1[3] = (f16)(e7 * inv);
  f16x4* orow = (f16x4*)row;
  orow[t]       = o0;
  orow[t + 256] = o1;
}

// ---------------------------------------------------------------------------
extern "C" void kernel_launch(void* const* d_in, const int* in_sizes, int n_in,
                              void* d_out, int out_size, void* d_ws, size_t ws_size,
                              hipStream_t stream)
{
  const float* x1   = (const float*)d_in[0];
  const float* x2   = (const float*)d_in[1];
  const float* U    = (const float*)d_in[2];
  const float* bias = (const float*)d_in[3];
  const float* fcw  = (const float*)d_in[4];
  const float* fcb  = (const float*)d_in[5];
  float* out = (float*)d_out;

  const int S = 2048, D = 1024, E = 512, B = 8;
  const size_t MB = 1ull << 20;
  const size_t KB64 = 64 * 1024;

  // FULL (ws >= 21,037,056 B, proven to trigger in R11):
  //   W2 4MB | bT 64KB | Sb 16MB (f32, full batch) = 20.06 MB
  //   Uh in Sb bytes [13MB,15MB) — recreated per batch, consumed by K0 BEFORE
  //   K2 overwrites Sb. NO Fh in FULL (R14 bug: K2 destroyed it before W1T);
  //   W1T is computed from fcw f32 (identical rounding) into Sb row-tails
  //   AFTER softmax. Fallback: exact champion layout (17.06 MB).
  const bool FULL = ws_size >= (4 * MB + KB64 + 16 * MB);

  char* w = (char*)d_ws;
  f16*   W2   = (f16*)(w);
  f16*   W1Tf = (f16*)(w + 4 * MB);                 // fallback only
  float* bT   = FULL ? (float*)(w + 4 * MB) : (float*)(w + 6 * MB);
  float* Sb   = FULL ? (float*)(w + 4 * MB + KB64) : (float*)(w + 6 * MB + KB64);
  f16*   Uh   = FULL ? (f16*)((char*)Sb + 13 * MB) : (f16*)(w + 14 * MB + KB64);
  f16*   Fh   = (f16*)(w + 16 * MB + KB64);         // fallback only
  f16*   W1T  = FULL ? (f16*)Sb + 2048 : W1Tf;      // FULL: row-tails, ld 4096
  const int ldw1t = FULL ? 2 * S : S;

  // X2h_all overlays d_out exactly (row s of out[b] aliases row s of X2h[b]).
  // K4' writes out[b] rows only AFTER K2 consumed them (stream-ordered).
  f16* X2h = (f16*)d_out;

  copy_f32_f16<<<dim3(B * S * D / 2048), 256, 0, stream>>>(x2, X2h);
  bias_dot<<<dim3(B * S / 4), 256, 0, stream>>>(x1, bias, bT);
  if (!FULL)
    copy_uf<<<dim3(768), 256, 0, stream>>>(U, fcw, Uh, Fh);

  for (int b = 0; b < B; b++) {
    const float* x1b = x1 + (size_t)b * S * D;
    const f16*   X2b = X2h + (size_t)b * S * D;

    if (FULL) {
      // Recreate Uh in Sb scratch (destroyed by previous batch's K2); U only.
      copy_uf<<<dim3(512), 256, 0, stream>>>(U, fcw, Uh, nullptr);

      // K0: W2[t][d] = sum_e x1b[t,e] Uh[d,e]   grid (32,8)=256
      gemm_tn<64, 128, float, f16, false, false, f16><<<dim3(S / 64, D / 128), 256, 0, stream>>>(
          x1b, D, Uh, D, W2, D, nullptr, D);

      // K2 full, 128x128 tile (4x4 frags/wave): grid (16,16)=256, 1/CU
      gemm_tn<128, 128, f16, f16, true, false, float><<<dim3(S / 128, S / 128), 256, 0, stream>>>(
          X2b, D, W2, D, Sb, S, bT + (size_t)b * S, D);

      // softmax all 2048 rows -> P f16 packed into row heads
      softmax_rows<<<dim3(S), 256, 0, stream>>>(Sb);

      // W1T[e][t] into Sb row-tails (dead after softmax), from fcw f32 directly
      // (staged values == (f16)fcw — bit-identical to the Fh path)
      gemm_tn<64, 64, float, float, false, false, f16><<<dim3(E / 64, S / 64), 256, 0, stream>>>(
          fcw, D, x1b, D, W1T, ldw1t, nullptr, D);

      // K4' full: out[b] = relu(P @ W1T^T + fcb)   grid (32,8)=256
      gemm_tn<64, 64, f16, f16, true, true, float><<<dim3(S / 64, E / 64), 256, 0, stream>>>(
          (const f16*)Sb, 2 * S, W1T, ldw1t, out + (size_t)b * S * E, E, fcb, S);
    } else {
      // === exact champion (R10 fallback) ===
      gemm_tn<64, 128, float, f16, false, false, f16><<<dim3(S / 64, D / 128), 256, 0, stream>>>(
          x1b, D, Uh, D, W2, D, nullptr, D);
      gemm_tn<64, 64, f16, float, false, false, f16><<<dim3(E / 64, S / 64), 256, 0, stream>>>(
          Fh, D, x1b, D, W1Tf, S, nullptr, D);
      for (int s0 = 0; s0 < S; s0 += 1024) {
        gemm_tn<64, 128, f16, f16, true, false, float><<<dim3(1024 / 64, S / 128), 256, 0, stream>>>(
            X2b + (size_t)s0 * D, D, W2, D, Sb, S, bT + (size_t)b * S, D);
        softmax_rows<<<dim3(1024), 256, 0, stream>>>(Sb);
        gemm_tn<64, 64, f16, f16, true, true, float><<<dim3(1024 / 64, E / 64), 256, 0, stream>>>(
            (const f16*)Sb, 2 * S, W1Tf, S, out + ((size_t)b * S + s0) * E, E, fcb, S);
      }
    }
  }
}

// Round 16
// 700.849 us; speedup vs baseline: 1.1781x; 1.0294x over previous
//
#include <hip/hip_runtime.h>
#include <hip/hip_fp16.h>
#include <cstddef>
#include <cstdint>

typedef _Float16 f16;
typedef _Float16 f16x8 __attribute__((ext_vector_type(8)));
typedef _Float16 f16x4 __attribute__((ext_vector_type(4)));
typedef float    f32x4 __attribute__((ext_vector_type(4)));

#define BK 64   // K-tile depth (fp16 elems); 2 MFMA k-steps per tile

// async 16B global->LDS (linear LDS dest = wave-uniform base + lane*16)
__device__ __forceinline__ void gload16(const void* g, void* lds) {
  __builtin_amdgcn_global_load_lds(
      (const __attribute__((address_space(1))) unsigned int*)g,
      (__attribute__((address_space(3))) unsigned int*)lds, 16, 0, 0);
}

// Stage an [R x 64] fp16 tile via global_load_lds. LDS row r holds global
// 8-elem slot s at slot s^(r&7) (rule-21 both-sides swizzle).
template<int R>
__device__ __forceinline__ void stage_f16(f16 (*buf)[BK], const f16* __restrict__ src,
                                          int ld, int w, int lane) {
#pragma unroll
  for (int i = 0; i < R / 32; i++) {
    const int grp  = w * (R / 32) + i;          // wave-uniform
    const int r    = grp * 8 + (lane >> 3);
    const int slot = (lane & 7) ^ (r & 7);
    gload16(src + (size_t)r * ld + slot * 8, &buf[grp * 8][0]);
  }
}

// Reg-staging for f32 sources (T14 issue-early / write-late).
template<int R>
struct RegStage {
  static constexpr int NV = (R == 128) ? 8 : 4;
  float4 v[NV];
  __device__ __forceinline__ void load(const float* __restrict__ src, int ld, int tid) {
    const int r = (R == 128) ? (tid >> 1) : (tid >> 2);
    const int h = (R == 128) ? (tid & 1) * 32 : (tid & 3) * 16;
    const float* p = src + (size_t)r * ld + h;
#pragma unroll
    for (int j = 0; j < NV; j++) v[j] = ((const float4*)p)[j];
  }
  __device__ __forceinline__ void write(f16 (*buf)[BK], int tid) {
    const int r = (R == 128) ? (tid >> 1) : (tid >> 2);
    const int h = (R == 128) ? (tid & 1) * 32 : (tid & 3) * 16;
#pragma unroll
    for (int g = 0; g < NV / 2; g++) {
      const float4 a = v[g * 2], b = v[g * 2 + 1];
      f16x8 o;
      o[0] = (f16)a.x; o[1] = (f16)a.y; o[2] = (f16)a.z; o[3] = (f16)a.w;
      o[4] = (f16)b.x; o[5] = (f16)b.y; o[6] = (f16)b.z; o[7] = (f16)b.w;
      const int slot = (h / 8 + g) ^ (r & 7);
      *(f16x8*)&buf[r][slot * 8] = o;
    }
  }
};

// ---------------------------------------------------------------------------
// TN GEMM, double-buffered (proven core): C = A@B^T (+bias[n]) (+relu).
// fp16 operands: global_load_lds. f32 operands: reg-stage + cvt.
// Chunked bijective XCD swizzle on (bx,by); requires nxy % 8 == 0.
// ---------------------------------------------------------------------------
template<int BMt, int BNt, typename TA, typename TB, bool BIAS, bool RELU, typename TC>
__global__ __launch_bounds__(256, 2)
void gemm_tn(const TA* __restrict__ A, int lda,
             const TB* __restrict__ B, int ldb,
             TC* __restrict__ C, int ldc,
             const float* __restrict__ bias, int K)
{
  constexpr int MF = BMt / 32;
  constexpr int NF = BNt / 32;
  __shared__ f16 As[2][BMt][BK];
  __shared__ f16 Bs[2][BNt][BK];
  const int tid  = threadIdx.x;
  const int lane = tid & 63;
  const int w    = tid >> 6;
  const int wr   = w >> 1, wc = w & 1;

  const int gx = gridDim.x, nxy = gx * gridDim.y;
  int lin = blockIdx.y * gx + blockIdx.x;
  lin = (lin & 7) * (nxy >> 3) + (lin >> 3);
  const int m0 = (lin % gx) * BMt;
  const int n0 = (lin / gx) * BNt;

  f32x4 acc[MF][NF] = {};
  RegStage<BMt> ra;   // dead when TA == f16
  RegStage<BNt> rb;   // dead when TB == f16

  auto stage_issue = [&](int buf, int k0) {
    if constexpr (sizeof(TA) == 2)
      stage_f16<BMt>(As[buf], (const f16*)A + (size_t)m0 * lda + k0, lda, w, lane);
    else
      ra.load((const float*)A + (size_t)m0 * lda + k0, lda, tid);
    if constexpr (sizeof(TB) == 2)
      stage_f16<BNt>(Bs[buf], (const f16*)B + (size_t)n0 * ldb + k0, ldb, w, lane);
    else
      rb.load((const float*)B + (size_t)n0 * ldb + k0, ldb, tid);
  };
  auto stage_write = [&](int buf) {
    if constexpr (sizeof(TA) == 4) ra.write(As[buf], tid);
    if constexpr (sizeof(TB) == 4) rb.write(Bs[buf], tid);
  };
  auto compute = [&](int buf) {
    const int fr = lane & 15, q = lane >> 4;
#pragma unroll
    for (int kk = 0; kk < 2; kk++) {
      f16x8 af[MF], bf[NF];
#pragma unroll
      for (int i = 0; i < MF; i++) {
        const int r = wr * (BMt / 2) + i * 16 + fr;
        const int slot = (kk * 4 + q) ^ (r & 7);
        af[i] = *(const f16x8*)&As[buf][r][slot * 8];
      }
#pragma unroll
      for (int j = 0; j < NF; j++) {
        const int r = wc * (BNt / 2) + j * 16 + fr;
        const int slot = (kk * 4 + q) ^ (r & 7);
        bf[j] = *(const f16x8*)&Bs[buf][r][slot * 8];
      }
#pragma unroll
      for (int i = 0; i < MF; i++)
#pragma unroll
        for (int j = 0; j < NF; j++)
          acc[i][j] = __builtin_amdgcn_mfma_f32_16x16x32_f16(af[i], bf[j], acc[i][j], 0, 0, 0);
    }
  };

  stage_issue(0, 0);
  stage_write(0);
  __syncthreads();

  const int KT = K / BK;
  for (int kt = 0; kt < KT; kt++) {
    const int cur = kt & 1, nxt = cur ^ 1;
    if (kt + 1 < KT) stage_issue(nxt, (kt + 1) * BK);
    compute(cur);
    if (kt + 1 < KT) stage_write(nxt);
    __syncthreads();
  }

  const int fr = lane & 15;
  const int rg = (lane >> 4) << 2;
#pragma unroll
  for (int i = 0; i < MF; i++) {
#pragma unroll
    for (int j = 0; j < NF; j++) {
      const int col = n0 + wc * (BNt / 2) + j * 16 + fr;
      float bv = 0.f;
      if constexpr (BIAS) bv = bias[col];
#pragma unroll
      for (int r = 0; r < 4; r++) {
        const int row = m0 + wr * (BMt / 2) + i * 16 + rg + r;
        float v = acc[i][j][r] + bv;
        if constexpr (RELU) v = fmaxf(v, 0.f);
        C[(size_t)row * ldc + col] = (TC)v;
      }
    }
  }
}

// merged head: blocks [0,8192) -> x2 f32->f16 copy; [8192,12288) -> bT rows
__global__ __launch_bounds__(256)
void prep_head(const float* __restrict__ x2, f16* __restrict__ X2h,
               const float* __restrict__ x1, const float* __restrict__ bias,
               float* __restrict__ bT)
{
  if (blockIdx.x < 8192) {
    const size_t i = ((size_t)blockIdx.x * 256 + threadIdx.x) * 8;
    const float4 a = ((const float4*)(x2 + i))[0];
    const float4 b = ((const float4*)(x2 + i))[1];
    f16x8 v;
    v[0] = (f16)a.x; v[1] = (f16)a.y; v[2] = (f16)a.z; v[3] = (f16)a.w;
    v[4] = (f16)b.x; v[5] = (f16)b.y; v[6] = (f16)b.z; v[7] = (f16)b.w;
    *(f16x8*)(X2h + i) = v;
  } else {
    const int row  = (blockIdx.x - 8192) * 4 + (threadIdx.x >> 6);
    const int lane = threadIdx.x & 63;
    const float4* r = (const float4*)(x1 + (size_t)row * 1024);
    const float4* bb = (const float4*)bias;
    float acc = 0.f;
#pragma unroll
    for (int j = 0; j < 4; j++) {
      const float4 a = r[lane + j * 64];
      const float4 b = bb[lane + j * 64];
      acc += a.x * b.x + a.y * b.y + a.z * b.z + a.w * b.w;
    }
#pragma unroll
    for (int off = 32; off > 0; off >>= 1) acc += __shfl_xor(acc, off);
    if (lane == 0) bT[row] = acc;
  }
}

// f32 -> fp16 vector copy (8 elems/thread)
__global__ __launch_bounds__(256)
void copy_f32_f16(const float* __restrict__ in, f16* __restrict__ o)
{
  const size_t i = ((size_t)blockIdx.x * 256 + threadIdx.x) * 8;
  const float4 a = ((const float4*)(in + i))[0];
  const float4 b = ((const float4*)(in + i))[1];
  f16x8 v;
  v[0] = (f16)a.x; v[1] = (f16)a.y; v[2] = (f16)a.z; v[3] = (f16)a.w;
  v[4] = (f16)b.x; v[5] = (f16)b.y; v[6] = (f16)b.z; v[7] = (f16)b.w;
  *(f16x8*)(o + i) = v;
}

// merged U->Uh (blocks 0..511) and fcw->Fh (blocks 512..767); grid 512 = U only
__global__ __launch_bounds__(256)
void copy_uf(const float* __restrict__ U, const float* __restrict__ fcw,
             f16* __restrict__ Uh, f16* __restrict__ Fh)
{
  const bool isU = blockIdx.x < 512;
  const size_t base = (size_t)(isU ? blockIdx.x : blockIdx.x - 512) * 2048;
  const float* in = (isU ? U : fcw) + base;
  f16* o = (isU ? Uh : Fh) + base;
  const size_t i = (size_t)threadIdx.x * 8;
  const float4 a = ((const float4*)(in + i))[0];
  const float4 b = ((const float4*)(in + i))[1];
  f16x8 v;
  v[0] = (f16)a.x; v[1] = (f16)a.y; v[2] = (f16)a.z; v[3] = (f16)a.w;
  v[4] = (f16)b.x; v[5] = (f16)b.y; v[6] = (f16)b.z; v[7] = (f16)b.w;
  *(f16x8*)(o + i) = v;
}

// ---------------------------------------------------------------------------
// Wave-per-row softmax: one wave owns a full 2048-f32 row (32 f32/lane,
// all-register, shuffle-only — no LDS, no barriers). Writes P f16 packed
// into the first 4KB of the row. Grid = rows/4, 256 thr (4 waves).
// ---------------------------------------------------------------------------
__global__ __launch_bounds__(256)
void softmax_rows_w(float* __restrict__ S)
{
  const int row  = blockIdx.x * 4 + (threadIdx.x >> 6);
  const int lane = threadIdx.x & 63;
  float* rp = S + (size_t)row * 2048;
  const float4* pr = (const float4*)rp + lane;   // f32 elems 4*lane + 256*k

  float f[32];
  float m = -3.4e38f;
#pragma unroll
  for (int k = 0; k < 8; k++) {
    const float4 v = pr[(size_t)k * 64];
    f[k * 4 + 0] = v.x; f[k * 4 + 1] = v.y; f[k * 4 + 2] = v.z; f[k * 4 + 3] = v.w;
    m = fmaxf(m, fmaxf(fmaxf(v.x, v.y), fmaxf(v.z, v.w)));
  }
#pragma unroll
  for (int off = 32; off > 0; off >>= 1) m = fmaxf(m, __shfl_xor(m, off));

  float s = 0.f;
#pragma unroll
  for (int i = 0; i < 32; i++) { f[i] = __expf(f[i] - m); s += f[i]; }
#pragma unroll
  for (int off = 32; off > 0; off >>= 1) s += __shfl_xor(s, off);
  const float inv = 1.f / s;

  // write f16x4 per k at elems 4*lane + 256*k (coalesced 512B per k)
  f16* hp = (f16*)rp;
#pragma unroll
  for (int k = 0; k < 8; k++) {
    f16x4 o;
    o[0] = (f16)(f[k * 4 + 0] * inv); o[1] = (f16)(f[k * 4 + 1] * inv);
    o[2] = (f16)(f[k * 4 + 2] * inv); o[3] = (f16)(f[k * 4 + 3] * inv);
    *(f16x4*)(hp + 4 * lane + 256 * k) = o;
  }
}

// ---------------------------------------------------------------------------
extern "C" void kernel_launch(void* const* d_in, const int* in_sizes, int n_in,
                              void* d_out, int out_size, void* d_ws, size_t ws_size,
                              hipStream_t stream)
{
  const float* x1   = (const float*)d_in[0];
  const float* x2   = (const float*)d_in[1];
  const float* U    = (const float*)d_in[2];
  const float* bias = (const float*)d_in[3];
  const float* fcw  = (const float*)d_in[4];
  const float* fcb  = (const float*)d_in[5];
  float* out = (float*)d_out;

  const int S = 2048, D = 1024, E = 512, B = 8;
  const size_t MB = 1ull << 20;
  const size_t KB64 = 64 * 1024;

  // MODE2 (ws >= 23,134,208 — probe): W2 4 | bT 64K | Uh 2 | Sb 16 = 22.06 MiB
  //   -> dedicated Uh, no per-batch copy_uf.
  // MODE1 (ws >= 21,037,056 — R15-proven): W2 4 | bT 64K | Sb 16; Uh in Sb
  //   scratch, recreated per batch (consumed by K0 before K2 overwrites).
  // MODE0: exact R10 champion fallback (17.06 MiB).
  const int MODE = (ws_size >= 4 * MB + KB64 + 2 * MB + 16 * MB) ? 2
                 : (ws_size >= 4 * MB + KB64 + 16 * MB)          ? 1 : 0;

  char* w = (char*)d_ws;
  f16*   W2   = (f16*)(w);
  f16*   W1Tf = (f16*)(w + 4 * MB);                       // MODE0 only
  float* bT   = MODE ? (float*)(w + 4 * MB) : (float*)(w + 6 * MB);
  float* Sb   = (MODE == 2) ? (float*)(w + 6 * MB + KB64)
              : MODE        ? (float*)(w + 4 * MB + KB64)
                            : (float*)(w + 6 * MB + KB64);
  f16*   Uh   = (MODE == 2) ? (f16*)(w + 4 * MB + KB64)   // dedicated
              : MODE        ? (f16*)((char*)Sb + 13 * MB) // Sb scratch
                            : (f16*)(w + 14 * MB + KB64);
  f16*   Fh   = (f16*)(w + 16 * MB + KB64);               // MODE0 only
  f16*   W1T  = MODE ? (f16*)Sb + 2048 : W1Tf;            // MODE1/2: row-tails
  const int ldw1t = MODE ? 2 * S : S;

  // X2h_all overlays d_out exactly (row s of out[b] aliases row s of X2h[b]).
  // K4' writes out[b] rows only AFTER K2 consumed them (stream-ordered).
  f16* X2h = (f16*)d_out;

  prep_head<<<dim3(8192 + 4096), 256, 0, stream>>>(x2, X2h, x1, bias, bT);
  if (MODE == 2)
    copy_uf<<<dim3(512), 256, 0, stream>>>(U, fcw, Uh, nullptr);
  else if (MODE == 0)
    copy_uf<<<dim3(768), 256, 0, stream>>>(U, fcw, Uh, Fh);

  for (int b = 0; b < B; b++) {
    const float* x1b = x1 + (size_t)b * S * D;
    const f16*   X2b = X2h + (size_t)b * S * D;

    if (MODE) {
      if (MODE == 1)  // recreate Uh in Sb scratch (destroyed by prev K2)
        copy_uf<<<dim3(512), 256, 0, stream>>>(U, fcw, Uh, nullptr);

      // K0: W2[t][d] = sum_e x1b[t,e] Uh[d,e]   grid (32,8)=256
      gemm_tn<64, 128, float, f16, false, false, f16><<<dim3(S / 64, D / 128), 256, 0, stream>>>(
          x1b, D, Uh, D, W2, D, nullptr, D);

      // K2 full, 128x128 tile: grid (16,16)=256, 1/CU
      gemm_tn<128, 128, f16, f16, true, false, float><<<dim3(S / 128, S / 128), 256, 0, stream>>>(
          X2b, D, W2, D, Sb, S, bT + (size_t)b * S, D);

      // softmax all 2048 rows (wave-per-row), grid 512
      softmax_rows_w<<<dim3(S / 4), 256, 0, stream>>>(Sb);

      // W1T[e][t] into Sb row-tails (dead after softmax), fcw f32 directly
      gemm_tn<64, 64, float, float, false, false, f16><<<dim3(E / 64, S / 64), 256, 0, stream>>>(
          fcw, D, x1b, D, W1T, ldw1t, nullptr, D);

      // K4' full: out[b] = relu(P @ W1T^T + fcb)   grid (32,8)=256
      gemm_tn<64, 64, f16, f16, true, true, float><<<dim3(S / 64, E / 64), 256, 0, stream>>>(
          (const f16*)Sb, 2 * S, W1T, ldw1t, out + (size_t)b * S * E, E, fcb, S);
    } else {
      // === exact R10 champion fallback ===
      gemm_tn<64, 128, float, f16, false, false, f16><<<dim3(S / 64, D / 128), 256, 0, stream>>>(
          x1b, D, Uh, D, W2, D, nullptr, D);
      gemm_tn<64, 64, f16, float, false, false, f16><<<dim3(E / 64, S / 64), 256, 0, stream>>>(
          Fh, D, x1b, D, W1Tf, S, nullptr, D);
      for (int s0 = 0; s0 < S; s0 += 1024) {
        gemm_tn<64, 128, f16, f16, true, false, float><<<dim3(1024 / 64, S / 128), 256, 0, stream>>>(
            X2b + (size_t)s0 * D, D, W2, D, Sb, S, bT + (size_t)b * S, D);
        softmax_rows_w<<<dim3(1024 / 4), 256, 0, stream>>>(Sb);
        gemm_tn<64, 64, f16, f16, true, true, float><<<dim3(1024 / 64, E / 64), 256, 0, stream>>>(
            (const f16*)Sb, 2 * S, W1Tf, S, out + ((size_t)b * S + s0) * E, E, fcb, S);
      }
    }
  }
}